// Round 6
// baseline (242.737 us; speedup 1.0000x reference)
//
#include <hip/hip_runtime.h>
#include <stdint.h>
#include <math.h>

typedef unsigned short u16;
typedef __attribute__((ext_vector_type(8))) short short8;
typedef __attribute__((ext_vector_type(4))) float floatx4;

#define DEV static __device__ __forceinline__

struct alignas(8) us4 { u16 x, y, z, w; };
struct alignas(16) us8 { u16 v[8]; };
struct alignas(16) f4 { float x, y, z, w; };
struct alignas(8) f2 { float x, y; };
struct alignas(8) u32x2 { uint32_t x, y; };

DEV u16 f2bf(float f) {
  uint32_t u = __float_as_uint(f);
  u += 0x7fffu + ((u >> 16) & 1u);
  return (u16)(u >> 16);
}
DEV float bf2f(u16 h) { return __uint_as_float(((uint32_t)h) << 16); }

DEV uint32_t pkbf(float a, float b) {
#if __has_builtin(__builtin_amdgcn_cvt_pk_bf16_f32)
  typedef __attribute__((ext_vector_type(2))) __bf16 bf2_t;
  bf2_t v = __builtin_amdgcn_cvt_pk_bf16_f32(a, b);
  uint32_t r; __builtin_memcpy(&r, &v, 4); return r;
#else
  return (uint32_t)f2bf(a) | ((uint32_t)f2bf(b) << 16);
#endif
}

DEV float fexp2(float x) {
#if __has_builtin(__builtin_amdgcn_exp2f)
  return __builtin_amdgcn_exp2f(x);
#else
  return exp2f(x);
#endif
}

DEV void load_lds16(const void* g, void* l) {
  __builtin_amdgcn_global_load_lds((const __attribute__((address_space(1))) void*)g,
                                   (__attribute__((address_space(3))) void*)l, 16, 0, 0);
}

// ---------------- fused prologue: cvt hidden + transpose both weights ----------------
__global__ __launch_bounds__(256) void prep_fused(const float* __restrict__ hidden, u16* __restrict__ h_bf,
                                                  const float* __restrict__ attn_w, u16* __restrict__ wqkvT,
                                                  const float* __restrict__ proj_w, u16* __restrict__ wprojT) {
  __shared__ float tile[32][33];
  const int bx = blockIdx.x;
  const int t = threadIdx.x;
  if (bx < 4096) {
    const int i = (bx * 256 + t) * 4;
    f4 v = *(const f4*)(hidden + i);
    us4 o; o.x = f2bf(v.x); o.y = f2bf(v.y); o.z = f2bf(v.z); o.w = f2bf(v.w);
    *(us4*)(h_bf + i) = o;
    return;
  }
  const float* in; u16* out; int K, N, n0, k0;
  if (bx < 7168) {
    const int bid = bx - 4096;  // 96 x 32
    in = attn_w; out = wqkvT; K = 1024; N = 3072;
    n0 = (bid % 96) * 32; k0 = (bid / 96) * 32;
  } else {
    const int bid = bx - 7168;  // 32 x 32
    in = proj_w; out = wprojT; K = 1024; N = 1024;
    n0 = (bid & 31) * 32; k0 = (bid >> 5) * 32;
  }
  const int tx = t & 31, ty = t >> 5;
  for (int i = ty; i < 32; i += 8)
    tile[i][tx] = in[(size_t)(k0 + i) * N + n0 + tx];
  __syncthreads();
  for (int i = ty; i < 32; i += 8)
    out[(size_t)(n0 + i) * K + k0 + tx] = f2bf(tile[tx][i]);
}

// ---------------- bf16 GEMM, C = A[M,K] * Bt[N,K]^T + bias ----------------
template <int EPI, int BN, int NGRP>
__global__ __launch_bounds__(256) void gemm_bt(const u16* __restrict__ A,
                                               const u16* __restrict__ Bt,
                                               const float* __restrict__ bias,
                                               void* __restrict__ outp,
                                               int M, int N, int K) {
  constexpr int NT = BN / 32;
  __shared__ u16 lA[128 * 64];
  __shared__ u16 lB[BN * 64];
  const int t = threadIdx.x;
  const int w = t >> 6, lane = t & 63;
  const int quad = lane >> 4, l15 = lane & 15;
  const int wm = w >> 1, wn = w & 1;
  const int wn_off = wn * (BN / 2);

  const int bid = blockIdx.x;
  const int gsz = 32 * NGRP;
  const int grp = bid / gsz;
  const int r = bid - grp * gsz;
  const int m0 = (r & 31) * 128;
  const int n0 = (grp * NGRP + (r >> 5)) * BN;

  floatx4 acc[4][NT] = {};

  const int srow = t >> 3;
  const int scol = (((t & 7) ^ (srow & 7)) << 3);
  const u16* gA = A + (size_t)(m0 + srow) * K + scol;
  const u16* gB = Bt + (size_t)(n0 + srow) * K + scol;
  u16* sA = lA + t * 8;
  u16* sB = lB + t * 8;
  const size_t rstep = (size_t)32 * K;

  for (int k0 = 0; k0 < K; k0 += 64) {
#pragma unroll
    for (int c = 0; c < 4; c++) load_lds16(gA + c * rstep, sA + c * 2048);
#pragma unroll
    for (int c = 0; c < BN / 32; c++) load_lds16(gB + c * rstep, sB + c * 2048);
    gA += 64; gB += 64;
    __syncthreads();
#pragma unroll
    for (int kc = 0; kc < 2; kc++) {
      short8 af[4], bfr[NT];
#pragma unroll
      for (int mt = 0; mt < 4; mt++)
        af[mt] = *(const short8*)&lA[(wm * 64 + mt * 16 + l15) * 64 + (((kc * 4 + quad) ^ (l15 & 7)) << 3)];
#pragma unroll
      for (int nt = 0; nt < NT; nt++)
        bfr[nt] = *(const short8*)&lB[(wn_off + nt * 16 + l15) * 64 + (((kc * 4 + quad) ^ (l15 & 7)) << 3)];
#pragma unroll
      for (int mt = 0; mt < 4; mt++)
#pragma unroll
        for (int nt = 0; nt < NT; nt++)
          acc[mt][nt] = __builtin_amdgcn_mfma_f32_16x16x32_bf16(bfr[nt], af[mt], acc[mt][nt], 0, 0, 0);
    }
    __syncthreads();
  }

  if (EPI == 0) {
    u16* outq = (u16*)outp;
#pragma unroll
    for (int nt = 0; nt < NT; nt++) {
      const int nb = n0 + wn_off + nt * 16 + quad * 4;
      const f4 bn4 = *(const f4*)&bias[nb];
      const int tensor = nb >> 10, e = nb & 1023;
      const int h = e >> 6, d = e & 63;
      const size_t abase = (size_t)tensor * 4194304 + (size_t)h * 131072 + d;
#pragma unroll
      for (int mt = 0; mt < 4; mt++) {
        const int rr = m0 + wm * 64 + mt * 16 + l15;
        const int b = rr >> 11, s = rr & 2047;
        u32x2 o;
        o.x = pkbf(acc[mt][nt][0] + bn4.x, acc[mt][nt][1] + bn4.y);
        o.y = pkbf(acc[mt][nt][2] + bn4.z, acc[mt][nt][3] + bn4.w);
        *(u32x2*)&outq[abase + (size_t)b * 2097152 + (size_t)s * 64] = o;
      }
    }
  } else {
    float* outf = (float*)outp;
#pragma unroll
    for (int nt = 0; nt < NT; nt++) {
      const int nb = n0 + wn_off + nt * 16 + quad * 4;
      const f4 bn4 = *(const f4*)&bias[nb];
#pragma unroll
      for (int mt = 0; mt < 4; mt++) {
        const int rr = m0 + wm * 64 + mt * 16 + l15;
        f4 o;
        o.x = acc[mt][nt][0] + bn4.x;
        o.y = acc[mt][nt][1] + bn4.y;
        o.z = acc[mt][nt][2] + bn4.z;
        o.w = acc[mt][nt][3] + bn4.w;
        *(f4*)&outf[(size_t)rr * N + nb] = o;
      }
    }
  }
}

// ---------------- causal depthwise conv / head-mix (register sliding window) ----------------
struct ConvW { const float* w[9]; const float* b[9]; };

template <int K>
DEV void conv_run(const u16* xt, int sl0, int d, const float* wp, const float* bp,
                  float qscale, float* out32) {
  float wr[K];
#pragma unroll
  for (int j = 0; j < K; j++) wr[j] = wp[d * K + j];
  const float br = bp[d];
  float win[K];
#pragma unroll
  for (int m = 1; m < K; m++) win[m] = bf2f(xt[(sl0 + 6 - K + m) * 68 + d]);
#pragma unroll
  for (int i = 0; i < 32; i++) {
#pragma unroll
    for (int m = 0; m < K - 1; m++) win[m] = win[m + 1];
    win[K - 1] = bf2f(xt[(sl0 + 6 + i) * 68 + d]);
    float val = br;
#pragma unroll
    for (int j = 0; j < K; j++) val += wr[j] * win[j];
    out32[i] = val * qscale;
  }
}

__global__ __launch_bounds__(256) void conv_mix(const u16* __restrict__ qkv, ConvW cw,
                                                u16* __restrict__ qpost,
                                                u16* __restrict__ kpost,
                                                u16* __restrict__ vpostT) {
  __shared__ u16 xt[134 * 68];
  __shared__ u16 yt[64 * 136];
  const int t = threadIdx.x;
  const int s0 = blockIdx.x * 128;
  const int h = blockIdx.y;
  const int tz = blockIdx.z;
  const int tensor = tz >> 1, b = tz & 1;
  const u16* src = qkv + (((size_t)tensor * 2 + b) * 16 + h) * 131072;

  for (int idx = t; idx < 134 * 16; idx += 256) {
    const int row = idx >> 4, c4 = (idx & 15) << 2;
    const int s = s0 - 6 + row;
    us4 v = {0, 0, 0, 0};
    if (s >= 0) v = *(const us4*)&src[(size_t)s * 64 + c4];
    *(us4*)&xt[row * 68 + c4] = v;
  }
  __syncthreads();

  const int group = h >> 2;
  const float* wp = (group > 0) ? cw.w[tensor * 3 + group - 1] : nullptr;
  const float* bp = (group > 0) ? cw.b[tensor * 3 + group - 1] : nullptr;
  const float qscale = (tensor == 0) ? 0.18033688f : 1.0f;

  const int d = t & 63;
  const int sl0 = (t >> 6) * 32;

  float out32[32];
  if (group == 0) {
#pragma unroll
    for (int i = 0; i < 32; i++)
      out32[i] = bf2f(xt[(sl0 + 6 + i) * 68 + d]) * qscale;
  } else if (group == 1) {
    conv_run<3>(xt, sl0, d, wp, bp, qscale, out32);
  } else if (group == 2) {
    conv_run<5>(xt, sl0, d, wp, bp, qscale, out32);
  } else {
    conv_run<7>(xt, sl0, d, wp, bp, qscale, out32);
  }

  if (tensor < 2) {
    u16* outp = (tensor == 0) ? qpost : kpost;
    const size_t ob = (((size_t)b * 16 + h) * 2048 + s0) * 64;
#pragma unroll
    for (int i = 0; i < 32; i++)
      outp[ob + (size_t)(sl0 + i) * 64 + d] = f2bf(out32[i]);
  } else {
#pragma unroll
    for (int i = 0; i < 32; i++)
      yt[d * 136 + sl0 + i] = f2bf(out32[i]);
    __syncthreads();
    const size_t ob = ((size_t)b * 16 + h) * 64;
    const int sl = (t & 15) * 8;
#pragma unroll
    for (int pass = 0; pass < 4; pass++) {
      const int dd = (t >> 4) + pass * 16;
      us8 vv = *(const us8*)&yt[dd * 136 + sl];
      *(us8*)&vpostT[(ob + dd) * 2048 + s0 + sl] = vv;
    }
  }
}

// ---------------- hybrid split-causal flash attention ----------------
// R5 diagnosis: duration = (longest kv-chain = 16 tiles) x (per-tile latency ~3us).
// Fix: cap chains at 8 tiles. qi<8 -> one block, whole row. qi>=8 -> two blocks,
// kv-slabs [0,8) and [8,qi+1). 24 blocks/bh -> 768 blocks (512 resident + 256
// backfill). LPT dispatch order (8-tile chains first) so backfill runs the short
// chains. No-max softmax gives all partials a SHARED 2^0 scale -> reduce is just
// O=(O1+O2)/(l1+l2). Double-buffered staging pipeline kept from R5.
static __device__ const unsigned char kOrder[24] = {
  7, 8, 10, 12, 14, 16, 18, 20, 22, 23,   // 8-tile chains
  6, 21, 5, 19, 4, 17, 3, 15, 2, 13, 1, 11, 0, 9  // 7,7,6,6,5,5,4,4,3,3,2,2,1,1
};

__global__ __launch_bounds__(256) void attn_fwd(const u16* __restrict__ Q,
                                                const u16* __restrict__ Kp,
                                                const u16* __restrict__ Vt,
                                                u16* __restrict__ Out,
                                                u16* __restrict__ Opart,
                                                float* __restrict__ lpart) {
  __shared__ u16 lK[2][128 * 64];    // [buf][kv][d]
  __shared__ u16 lV[2][64 * 128];    // [buf][d][kv]
  __shared__ u16 lP[4][32 * 64];     // per wave: [q_local][kv half]
  const int t = threadIdx.x;
  const int w = t >> 6, lane = t & 63;
  const int quad = lane >> 4, l15 = lane & 15;
  const int e7 = l15 & 7;

  const int lin = blockIdx.x;        // 768 blocks
  const int xcd = lin & 7;
  const int rest = lin >> 3;         // 0..95
  const int grp = rest / 24;         // 0..3
  const int slot = kOrder[rest - grp * 24];
  const int bh = grp * 8 + xcd;

  int qi, jbeg, jend, split, half;
  if (slot < 8) {
    qi = slot; jbeg = 0; jend = qi + 1; split = 0; half = 0;
  } else {
    const int k = slot - 8;
    qi = 8 + (k >> 1); half = k & 1;
    jbeg = half ? 8 : 0; jend = half ? qi + 1 : 8; split = 1;
  }

  const int b = bh >> 4, h = bh & 15;
  const size_t qkbase = (size_t)bh * 131072;
  const int qblk = qi * 128 + w * 32;

  const int krow = t >> 3;
  const int kcol = (((t & 7) ^ (krow & 7)) << 3);
  const u16* gK = Kp + qkbase + (size_t)krow * 64 + kcol;
  const int vrow = t >> 4;
  const int vcol = (((t & 15) ^ vrow) << 3);
  const u16* gV = Vt + qkbase + (size_t)vrow * 2048 + vcol;
  u16* myP = lP[w];

  // ---- Q fragments (drained by the prologue vmcnt(0)) ----
  short8 qf[2][2];
#pragma unroll
  for (int qt = 0; qt < 2; qt++)
#pragma unroll
    for (int kc = 0; kc < 2; kc++)
      qf[qt][kc] = *(const short8*)&Q[qkbase + (size_t)(qblk + qt * 16 + l15) * 64 + kc * 32 + quad * 8];

  // ---- prologue: stage tile jbeg into buf0 ----
  {
    const int j0 = jbeg * 128;
    u16* sK = &lK[0][0] + t * 8;
    u16* sV = &lV[0][0] + t * 8;
#pragma unroll
    for (int c = 0; c < 4; c++) {
      load_lds16(gK + (size_t)(j0 + c * 32) * 64, sK + c * 2048);
      load_lds16(gV + j0 + c * 16 * 2048, sV + c * 2048);
    }
  }
  asm volatile("s_waitcnt vmcnt(0)" ::: "memory");
  __builtin_amdgcn_s_barrier();

  float lst[2] = {0.0f, 0.0f};
  floatx4 accO[4][2] = {};

  for (int j = jbeg; j < jend; ++j) {
    const int cur = (j - jbeg) & 1;

    // issue next tile's staging FIRST: its latency hides under this tile's compute
    if (j + 1 < jend) {
      const int j0n = (j + 1) * 128;
      u16* sK = &lK[cur ^ 1][0] + t * 8;
      u16* sV = &lV[cur ^ 1][0] + t * 8;
#pragma unroll
      for (int c = 0; c < 4; c++) {
        load_lds16(gK + (size_t)(j0n + c * 32) * 64, sK + c * 2048);
        load_lds16(gV + j0n + c * 16 * 2048, sV + c * 2048);
      }
    }

    const int j0 = j * 128;
    const u16* cK = lK[cur];
    const u16* cV = lV[cur];

    // ---- QK^T ----
    floatx4 accS[8][2] = {};
    __builtin_amdgcn_s_setprio(1);
#pragma unroll
    for (int kvt = 0; kvt < 8; kvt++) {
#pragma unroll
      for (int kc = 0; kc < 2; kc++) {
        const short8 a = *(const short8*)&cK[(kvt * 16 + l15) * 64 + (((kc * 4 + quad) ^ e7) << 3)];
#pragma unroll
        for (int qt = 0; qt < 2; qt++)
          accS[kvt][qt] = __builtin_amdgcn_mfma_f32_16x16x32_bf16(a, qf[qt][kc], accS[kvt][qt], 0, 0, 0);
      }
    }
    __builtin_amdgcn_s_setprio(0);

    if (j == qi) {
#pragma unroll
      for (int qt = 0; qt < 2; qt++) {
        const int q = qblk + qt * 16 + l15;
#pragma unroll
        for (int kvt = 0; kvt < 8; kvt++)
#pragma unroll
          for (int r = 0; r < 4; r++) {
            const int kv = j0 + kvt * 16 + quad * 4 + r;
            if (kv > q) accS[kvt][qt][r] = -3.0e38f;
          }
      }
    }

    // no-max softmax: p = exp2(s) raw; masked -> exp2(-3e38) = 0 (R2-verified)
    uint32_t pk01[2][8], pk23[2][8];
#pragma unroll
    for (int qt = 0; qt < 2; qt++) {
      float ts = 0.0f;
#pragma unroll
      for (int kvt = 0; kvt < 8; kvt++) {
        const float p0 = fexp2(accS[kvt][qt][0]);
        const float p1 = fexp2(accS[kvt][qt][1]);
        const float p2 = fexp2(accS[kvt][qt][2]);
        const float p3 = fexp2(accS[kvt][qt][3]);
        ts += (p0 + p1) + (p2 + p3);
        pk01[qt][kvt] = pkbf(p0, p1);
        pk23[qt][kvt] = pkbf(p2, p3);
      }
      lst[qt] += ts;   // lane-partial; cross-lane reduce deferred to epilogue
    }

    // ---- PV in two kv-half passes through per-wave lP ----
#pragma unroll
    for (int kvh = 0; kvh < 2; kvh++) {
#pragma unroll
      for (int qt = 0; qt < 2; qt++) {
        const int prow = (qt * 16 + l15) * 64;
#pragma unroll
        for (int kt = 0; kt < 4; kt++) {
          const int kvt = kvh * 4 + kt;
          const int slotp = (kt * 2 + (quad >> 1)) ^ e7;
          u32x2 pk; pk.x = pk01[qt][kvt]; pk.y = pk23[qt][kvt];
          *(u32x2*)&myP[prow + slotp * 8 + (quad & 1) * 4] = pk;
        }
      }
      asm volatile("s_waitcnt lgkmcnt(0)" ::: "memory");
      __builtin_amdgcn_s_setprio(1);
#pragma unroll
      for (int kk = 0; kk < 2; kk++) {
        const int kvc = kvh * 2 + kk;
        short8 pf[2];
#pragma unroll
        for (int qt = 0; qt < 2; qt++)
          pf[qt] = *(const short8*)&myP[(qt * 16 + l15) * 64 + (((kk * 4 + quad) ^ e7) << 3)];
#pragma unroll
        for (int dt = 0; dt < 4; dt++) {
          const short8 vf = *(const short8*)&cV[(dt * 16 + l15) * 128 + (((kvc * 4 + quad) ^ l15) << 3)];
#pragma unroll
          for (int qt = 0; qt < 2; qt++)
            accO[dt][qt] = __builtin_amdgcn_mfma_f32_16x16x32_bf16(vf, pf[qt], accO[dt][qt], 0, 0, 0);
        }
      }
      __builtin_amdgcn_s_setprio(0);
    }

    if (j + 1 < jend) {
      asm volatile("s_waitcnt vmcnt(0)" ::: "memory");
      __builtin_amdgcn_s_barrier();
    }
  }

  // deferred cross-lane l reduction (butterfly over the 4 quads)
#pragma unroll
  for (int qt = 0; qt < 2; qt++) {
    lst[qt] += __shfl_xor(lst[qt], 16);
    lst[qt] += __shfl_xor(lst[qt], 32);
  }

  if (!split) {
#pragma unroll
    for (int qt = 0; qt < 2; qt++) {
      const float inv = 1.0f / lst[qt];
      const int q = qblk + qt * 16 + l15;
#pragma unroll
      for (int dt = 0; dt < 4; dt++) {
        u32x2 o;
        o.x = pkbf(accO[dt][qt][0] * inv, accO[dt][qt][1] * inv);
        o.y = pkbf(accO[dt][qt][2] * inv, accO[dt][qt][3] * inv);
        *(u32x2*)&Out[((size_t)b * 2048 + q) * 1024 + h * 64 + dt * 16 + quad * 4] = o;
      }
    }
  } else {
    const int pidx = (bh * 8 + (qi - 8)) * 2 + half;  // 0..511
    u16* op = Opart + (size_t)pidx * 8192;
#pragma unroll
    for (int qt = 0; qt < 2; qt++) {
      const int ql = w * 32 + qt * 16 + l15;
#pragma unroll
      for (int dt = 0; dt < 4; dt++) {
        u32x2 o;
        o.x = pkbf(accO[dt][qt][0], accO[dt][qt][1]);
        o.y = pkbf(accO[dt][qt][2], accO[dt][qt][3]);
        *(u32x2*)&op[(size_t)ql * 64 + dt * 16 + quad * 4] = o;
      }
      if (quad == 0) lpart[pidx * 128 + ql] = lst[qt];
    }
  }
}

// ---------------- two-slab reduction (shared 2^0 scale: plain sum) ----------------
__global__ __launch_bounds__(256) void attn_reduce(const u16* __restrict__ Opart,
                                                   const float* __restrict__ lpart,
                                                   u16* __restrict__ Out) {
  const int qr = blockIdx.x;         // 0..7 -> qi = 8+qr
  const int bh = blockIdx.y;
  const int b = bh >> 4, h = bh & 15;
  const int t = threadIdx.x;
  const int row = t >> 1, dh = (t & 1) * 32;
  const int pbase = (bh * 8 + qr) * 2;

  const float l1 = lpart[pbase * 128 + row];
  const float l2 = lpart[(pbase + 1) * 128 + row];
  const float inv = 1.0f / (l1 + l2);

  const u16* s1 = Opart + ((size_t)pbase * 128 + row) * 64 + dh;
  const u16* s2 = Opart + ((size_t)(pbase + 1) * 128 + row) * 64 + dh;
  u16* dst = Out + ((size_t)b * 2048 + (8 + qr) * 128 + row) * 1024 + h * 64 + dh;
#pragma unroll
  for (int i = 0; i < 4; i++) {
    us8 v1 = *(const us8*)&s1[i * 8];
    us8 v2 = *(const us8*)&s2[i * 8];
    float o[8];
#pragma unroll
    for (int e = 0; e < 8; e++) o[e] = (bf2f(v1.v[e]) + bf2f(v2.v[e])) * inv;
    us4 a, c;
    uint32_t w0 = pkbf(o[0], o[1]), w1 = pkbf(o[2], o[3]);
    uint32_t w2 = pkbf(o[4], o[5]), w3 = pkbf(o[6], o[7]);
    u32x2 lo; lo.x = w0; lo.y = w1;
    u32x2 hi; hi.x = w2; hi.y = w3;
    *(u32x2*)&dst[i * 8] = lo;
    *(u32x2*)&dst[i * 8 + 4] = hi;
    (void)a; (void)c;
  }
}

// ---------------- launcher ----------------
extern "C" void kernel_launch(void* const* d_in, const int* in_sizes, int n_in,
                              void* d_out, int out_size, void* d_ws, size_t ws_size,
                              hipStream_t stream) {
  (void)in_sizes; (void)n_in; (void)out_size; (void)ws_size;
  const float* hidden = (const float*)d_in[0];
  const float* attn_w = (const float*)d_in[1];
  const float* attn_b = (const float*)d_in[2];
  const float* proj_w = (const float*)d_in[3];
  const float* proj_b = (const float*)d_in[4];
  ConvW cw;
  for (int i = 0; i < 9; i++) {
    cw.w[i] = (const float*)d_in[5 + 2 * i];
    cw.b[i] = (const float*)d_in[6 + 2 * i];
  }

  uint8_t* ws = (uint8_t*)d_ws;
  u16* h_bf   = (u16*)(ws + 0);          //  8,388,608 B
  u16* wqkvT  = (u16*)(ws + 8388608);    //  6,291,456 B
  u16* qkvpre = (u16*)(ws + 14680064);   // 25,165,824 B  [3][2][16][2048][64]
  u16* qpost  = (u16*)(ws + 39845888);   //  8,388,608 B  [2][16][2048][64]
  u16* kpost  = (u16*)(ws + 48234496);   //  8,388,608 B
  u16* vpostT = (u16*)(ws + 56623104);   //  8,388,608 B  [2][16][64][2048]
  u16* attno  = (u16*)(ws + 65011712);   //  8,388,608 B  [2][2048][1024]
  u16* wprojT = (u16*)(ws + 73400320);   //  2,097,152 B
  u16* Opart  = (u16*)(ws + 0);          //  8,388,608 B  overlay on h_bf (dead)
  float* lpart = (float*)(ws + 8388608); //    262,144 B  overlay on wqkvT (dead)

  prep_fused<<<8192, 256, 0, stream>>>(hidden, h_bf, attn_w, wqkvT, proj_w, wprojT);
  gemm_bt<0, 128, 6><<<768, 256, 0, stream>>>(h_bf, wqkvT, attn_b, (void*)qkvpre, 4096, 3072, 1024);
  conv_mix<<<dim3(16, 16, 6), 256, 0, stream>>>(qkvpre, cw, qpost, kpost, vpostT);
  attn_fwd<<<dim3(768), 256, 0, stream>>>(qpost, kpost, vpostT, attno, Opart, lpart);
  attn_reduce<<<dim3(8, 32), 256, 0, stream>>>(Opart, lpart, attno);
  gemm_bt<1, 64, 8><<<512, 256, 0, stream>>>(attno, wprojT, proj_b, d_out, 4096, 1024, 1024);
}

// Round 7
// 235.955 us; speedup vs baseline: 1.0287x; 1.0287x over previous
//
#include <hip/hip_runtime.h>
#include <stdint.h>
#include <math.h>

typedef unsigned short u16;
typedef __attribute__((ext_vector_type(8))) short short8;
typedef __attribute__((ext_vector_type(4))) float floatx4;

#define DEV static __device__ __forceinline__

struct alignas(8) us4 { u16 x, y, z, w; };
struct alignas(16) us8 { u16 v[8]; };
struct alignas(16) f4 { float x, y, z, w; };
struct alignas(8) f2 { float x, y; };
struct alignas(8) u32x2 { uint32_t x, y; };

DEV u16 f2bf(float f) {
  uint32_t u = __float_as_uint(f);
  u += 0x7fffu + ((u >> 16) & 1u);
  return (u16)(u >> 16);
}
DEV float bf2f(u16 h) { return __uint_as_float(((uint32_t)h) << 16); }

DEV uint32_t pkbf(float a, float b) {
#if __has_builtin(__builtin_amdgcn_cvt_pk_bf16_f32)
  typedef __attribute__((ext_vector_type(2))) __bf16 bf2_t;
  bf2_t v = __builtin_amdgcn_cvt_pk_bf16_f32(a, b);
  uint32_t r; __builtin_memcpy(&r, &v, 4); return r;
#else
  return (uint32_t)f2bf(a) | ((uint32_t)f2bf(b) << 16);
#endif
}

DEV float fexp2(float x) {
#if __has_builtin(__builtin_amdgcn_exp2f)
  return __builtin_amdgcn_exp2f(x);
#else
  return exp2f(x);
#endif
}

DEV void load_lds16(const void* g, void* l) {
  __builtin_amdgcn_global_load_lds((const __attribute__((address_space(1))) void*)g,
                                   (__attribute__((address_space(3))) void*)l, 16, 0, 0);
}

// ---------------- fused prologue: cvt hidden + transpose both weights ----------------
__global__ __launch_bounds__(256) void prep_fused(const float* __restrict__ hidden, u16* __restrict__ h_bf,
                                                  const float* __restrict__ attn_w, u16* __restrict__ wqkvT,
                                                  const float* __restrict__ proj_w, u16* __restrict__ wprojT) {
  __shared__ float tile[32][33];
  const int bx = blockIdx.x;
  const int t = threadIdx.x;
  if (bx < 4096) {
    const int i = (bx * 256 + t) * 4;
    f4 v = *(const f4*)(hidden + i);
    us4 o; o.x = f2bf(v.x); o.y = f2bf(v.y); o.z = f2bf(v.z); o.w = f2bf(v.w);
    *(us4*)(h_bf + i) = o;
    return;
  }
  const float* in; u16* out; int K, N, n0, k0;
  if (bx < 7168) {
    const int bid = bx - 4096;  // 96 x 32
    in = attn_w; out = wqkvT; K = 1024; N = 3072;
    n0 = (bid % 96) * 32; k0 = (bid / 96) * 32;
  } else {
    const int bid = bx - 7168;  // 32 x 32
    in = proj_w; out = wprojT; K = 1024; N = 1024;
    n0 = (bid & 31) * 32; k0 = (bid >> 5) * 32;
  }
  const int tx = t & 31, ty = t >> 5;
  for (int i = ty; i < 32; i += 8)
    tile[i][tx] = in[(size_t)(k0 + i) * N + n0 + tx];
  __syncthreads();
  for (int i = ty; i < 32; i += 8)
    out[(size_t)(n0 + i) * K + k0 + tx] = f2bf(tile[tx][i]);
}

// ---------------- bf16 GEMM, C = A[M,K] * Bt[N,K]^T + bias ----------------
template <int EPI, int BN, int NGRP>
__global__ __launch_bounds__(256) void gemm_bt(const u16* __restrict__ A,
                                               const u16* __restrict__ Bt,
                                               const float* __restrict__ bias,
                                               void* __restrict__ outp,
                                               int M, int N, int K) {
  constexpr int NT = BN / 32;
  __shared__ u16 lA[128 * 64];
  __shared__ u16 lB[BN * 64];
  const int t = threadIdx.x;
  const int w = t >> 6, lane = t & 63;
  const int quad = lane >> 4, l15 = lane & 15;
  const int wm = w >> 1, wn = w & 1;
  const int wn_off = wn * (BN / 2);

  const int bid = blockIdx.x;
  const int gsz = 32 * NGRP;
  const int grp = bid / gsz;
  const int r = bid - grp * gsz;
  const int m0 = (r & 31) * 128;
  const int n0 = (grp * NGRP + (r >> 5)) * BN;

  floatx4 acc[4][NT] = {};

  const int srow = t >> 3;
  const int scol = (((t & 7) ^ (srow & 7)) << 3);
  const u16* gA = A + (size_t)(m0 + srow) * K + scol;
  const u16* gB = Bt + (size_t)(n0 + srow) * K + scol;
  u16* sA = lA + t * 8;
  u16* sB = lB + t * 8;
  const size_t rstep = (size_t)32 * K;

  for (int k0 = 0; k0 < K; k0 += 64) {
#pragma unroll
    for (int c = 0; c < 4; c++) load_lds16(gA + c * rstep, sA + c * 2048);
#pragma unroll
    for (int c = 0; c < BN / 32; c++) load_lds16(gB + c * rstep, sB + c * 2048);
    gA += 64; gB += 64;
    __syncthreads();
#pragma unroll
    for (int kc = 0; kc < 2; kc++) {
      short8 af[4], bfr[NT];
#pragma unroll
      for (int mt = 0; mt < 4; mt++)
        af[mt] = *(const short8*)&lA[(wm * 64 + mt * 16 + l15) * 64 + (((kc * 4 + quad) ^ (l15 & 7)) << 3)];
#pragma unroll
      for (int nt = 0; nt < NT; nt++)
        bfr[nt] = *(const short8*)&lB[(wn_off + nt * 16 + l15) * 64 + (((kc * 4 + quad) ^ (l15 & 7)) << 3)];
#pragma unroll
      for (int mt = 0; mt < 4; mt++)
#pragma unroll
        for (int nt = 0; nt < NT; nt++)
          acc[mt][nt] = __builtin_amdgcn_mfma_f32_16x16x32_bf16(bfr[nt], af[mt], acc[mt][nt], 0, 0, 0);
    }
    __syncthreads();
  }

  if (EPI == 0) {
    u16* outq = (u16*)outp;
#pragma unroll
    for (int nt = 0; nt < NT; nt++) {
      const int nb = n0 + wn_off + nt * 16 + quad * 4;
      const f4 bn4 = *(const f4*)&bias[nb];
      const int tensor = nb >> 10, e = nb & 1023;
      const int h = e >> 6, d = e & 63;
      const size_t abase = (size_t)tensor * 4194304 + (size_t)h * 131072 + d;
#pragma unroll
      for (int mt = 0; mt < 4; mt++) {
        const int rr = m0 + wm * 64 + mt * 16 + l15;
        const int b = rr >> 11, s = rr & 2047;
        u32x2 o;
        o.x = pkbf(acc[mt][nt][0] + bn4.x, acc[mt][nt][1] + bn4.y);
        o.y = pkbf(acc[mt][nt][2] + bn4.z, acc[mt][nt][3] + bn4.w);
        *(u32x2*)&outq[abase + (size_t)b * 2097152 + (size_t)s * 64] = o;
      }
    }
  } else {
    float* outf = (float*)outp;
#pragma unroll
    for (int nt = 0; nt < NT; nt++) {
      const int nb = n0 + wn_off + nt * 16 + quad * 4;
      const f4 bn4 = *(const f4*)&bias[nb];
#pragma unroll
      for (int mt = 0; mt < 4; mt++) {
        const int rr = m0 + wm * 64 + mt * 16 + l15;
        f4 o;
        o.x = acc[mt][nt][0] + bn4.x;
        o.y = acc[mt][nt][1] + bn4.y;
        o.z = acc[mt][nt][2] + bn4.z;
        o.w = acc[mt][nt][3] + bn4.w;
        *(f4*)&outf[(size_t)rr * N + nb] = o;
      }
    }
  }
}

// ---------------- causal depthwise conv / head-mix (register sliding window) ----------------
struct ConvW { const float* w[9]; const float* b[9]; };

template <int K>
DEV void conv_run(const u16* xt, int sl0, int d, const float* wp, const float* bp,
                  float qscale, float* out32) {
  float wr[K];
#pragma unroll
  for (int j = 0; j < K; j++) wr[j] = wp[d * K + j];
  const float br = bp[d];
  float win[K];
#pragma unroll
  for (int m = 1; m < K; m++) win[m] = bf2f(xt[(sl0 + 6 - K + m) * 68 + d]);
#pragma unroll
  for (int i = 0; i < 32; i++) {
#pragma unroll
    for (int m = 0; m < K - 1; m++) win[m] = win[m + 1];
    win[K - 1] = bf2f(xt[(sl0 + 6 + i) * 68 + d]);
    float val = br;
#pragma unroll
    for (int j = 0; j < K; j++) val += wr[j] * win[j];
    out32[i] = val * qscale;
  }
}

__global__ __launch_bounds__(256) void conv_mix(const u16* __restrict__ qkv, ConvW cw,
                                                u16* __restrict__ qpost,
                                                u16* __restrict__ kpost,
                                                u16* __restrict__ vpostT) {
  __shared__ u16 xt[134 * 68];
  __shared__ u16 yt[64 * 136];
  const int t = threadIdx.x;
  const int s0 = blockIdx.x * 128;
  const int h = blockIdx.y;
  const int tz = blockIdx.z;
  const int tensor = tz >> 1, b = tz & 1;
  const u16* src = qkv + (((size_t)tensor * 2 + b) * 16 + h) * 131072;

  for (int idx = t; idx < 134 * 16; idx += 256) {
    const int row = idx >> 4, c4 = (idx & 15) << 2;
    const int s = s0 - 6 + row;
    us4 v = {0, 0, 0, 0};
    if (s >= 0) v = *(const us4*)&src[(size_t)s * 64 + c4];
    *(us4*)&xt[row * 68 + c4] = v;
  }
  __syncthreads();

  const int group = h >> 2;
  const float* wp = (group > 0) ? cw.w[tensor * 3 + group - 1] : nullptr;
  const float* bp = (group > 0) ? cw.b[tensor * 3 + group - 1] : nullptr;
  const float qscale = (tensor == 0) ? 0.18033688f : 1.0f;

  const int d = t & 63;
  const int sl0 = (t >> 6) * 32;

  float out32[32];
  if (group == 0) {
#pragma unroll
    for (int i = 0; i < 32; i++)
      out32[i] = bf2f(xt[(sl0 + 6 + i) * 68 + d]) * qscale;
  } else if (group == 1) {
    conv_run<3>(xt, sl0, d, wp, bp, qscale, out32);
  } else if (group == 2) {
    conv_run<5>(xt, sl0, d, wp, bp, qscale, out32);
  } else {
    conv_run<7>(xt, sl0, d, wp, bp, qscale, out32);
  }

  if (tensor < 2) {
    u16* outp = (tensor == 0) ? qpost : kpost;
    const size_t ob = (((size_t)b * 16 + h) * 2048 + s0) * 64;
#pragma unroll
    for (int i = 0; i < 32; i++)
      outp[ob + (size_t)(sl0 + i) * 64 + d] = f2bf(out32[i]);
  } else {
#pragma unroll
    for (int i = 0; i < 32; i++)
      yt[d * 136 + sl0 + i] = f2bf(out32[i]);
    __syncthreads();
    const size_t ob = ((size_t)b * 16 + h) * 64;
    const int sl = (t & 15) * 8;
#pragma unroll
    for (int pass = 0; pass < 4; pass++) {
      const int dd = (t >> 4) + pass * 16;
      us8 vv = *(const us8*)&yt[dd * 136 + sl];
      *(us8*)&vpostT[(ob + dd) * 2048 + s0 + sl] = vv;
    }
  }
}

// ---------------- full-causal flash attention, split-drain pipeline ----------------
// R5 structure (512 long blocks, proven best) + counted-wait split drain:
// staging per tile issues K's 4 loads THEN V's 4 loads. Tile j consumes them as:
//   top:  vmcnt(4)+barrier  -> K(j) done (4 oldest; V(j) still in flight) -> QK^T
//   after QK^T: issue K(j+1),V(j+1) (other buffer; prior readers passed barriers)
//   after softmax: vmcnt(8)+barrier -> V(j) done (8 just-issued may remain) -> PV
// Each DMA gets a full compute phase to land instead of a cold vmcnt(0) drain.
// Raw s_barrier (not __syncthreads) so the compiler doesn't add its own drain.
__global__ __launch_bounds__(256) void attn_fwd(const u16* __restrict__ Q,
                                                const u16* __restrict__ Kp,
                                                const u16* __restrict__ Vt,
                                                u16* __restrict__ Out) {
  __shared__ u16 lK[2][128 * 64];    // [buf][kv][d]
  __shared__ u16 lV[2][64 * 128];    // [buf][d][kv]
  __shared__ u16 lP[4][32 * 64];     // per wave: [q_local][kv half]
  const int t = threadIdx.x;
  const int w = t >> 6, lane = t & 63;
  const int quad = lane >> 4, l15 = lane & 15;
  const int e7 = l15 & 7;

  const int lin = blockIdx.x;        // 512 blocks
  const int xcd = lin & 7;
  const int s = lin >> 3;            // 0..63 within XCD
  const int grp = s & 3;
  const int qsel = s >> 2;           // 0..15
  const int bh = grp * 8 + xcd;
  const int qi = (qsel < 8) ? qsel : 23 - qsel;  // co-resident pairs sum to 17 tiles

  const int b = bh >> 4, h = bh & 15;
  const size_t qkbase = (size_t)bh * 131072;
  const int qblk = qi * 128 + w * 32;

  const int krow = t >> 3;
  const int kcol = (((t & 7) ^ (krow & 7)) << 3);
  const u16* gK = Kp + qkbase + (size_t)krow * 64 + kcol;
  const int vrow = t >> 4;
  const int vcol = (((t & 15) ^ vrow) << 3);
  const u16* gV = Vt + qkbase + (size_t)vrow * 2048 + vcol;
  u16* myP = lP[w];

  // ---- Q fragments (issued FIRST: drained by the first vmcnt(4)) ----
  short8 qf[2][2];
#pragma unroll
  for (int qt = 0; qt < 2; qt++)
#pragma unroll
    for (int kc = 0; kc < 2; kc++)
      qf[qt][kc] = *(const short8*)&Q[qkbase + (size_t)(qblk + qt * 16 + l15) * 64 + kc * 32 + quad * 8];
  asm volatile("" ::: "memory");   // pin issue order: Q | K(0) | V(0)

  // ---- prologue: stage tile 0, K then V ----
  {
    u16* sK = &lK[0][0] + t * 8;
#pragma unroll
    for (int c = 0; c < 4; c++) load_lds16(gK + (size_t)(c * 32) * 64, sK + c * 2048);
    asm volatile("" ::: "memory");
    u16* sV = &lV[0][0] + t * 8;
#pragma unroll
    for (int c = 0; c < 4; c++) load_lds16(gV + c * 16 * 2048, sV + c * 2048);
    asm volatile("" ::: "memory");
  }

  float lst[2] = {0.0f, 0.0f};
  floatx4 accO[4][2] = {};

  for (int j = 0; j <= qi; ++j) {
    const int cur = j & 1;
    const int j0 = j * 128;
    const u16* cK = lK[cur];
    const u16* cV = lV[cur];

    // K(j) ready: wait 4-oldest (Q + K(j) done; V(j) may be in flight)
    asm volatile("s_waitcnt vmcnt(4)" ::: "memory");
    __builtin_amdgcn_s_barrier();

    // ---- QK^T ----
    floatx4 accS[8][2] = {};
    __builtin_amdgcn_s_setprio(1);
#pragma unroll
    for (int kvt = 0; kvt < 8; kvt++) {
#pragma unroll
      for (int kc = 0; kc < 2; kc++) {
        const short8 a = *(const short8*)&cK[(kvt * 16 + l15) * 64 + (((kc * 4 + quad) ^ e7) << 3)];
#pragma unroll
        for (int qt = 0; qt < 2; qt++)
          accS[kvt][qt] = __builtin_amdgcn_mfma_f32_16x16x32_bf16(a, qf[qt][kc], accS[kvt][qt], 0, 0, 0);
      }
    }
    __builtin_amdgcn_s_setprio(0);

    // ---- issue next tile's staging: K first, then V (into the other buffer) ----
    if (j < qi) {
      const int j0n = (j + 1) * 128;
      asm volatile("" ::: "memory");
      u16* sK = &lK[cur ^ 1][0] + t * 8;
#pragma unroll
      for (int c = 0; c < 4; c++) load_lds16(gK + (size_t)(j0n + c * 32) * 64, sK + c * 2048);
      asm volatile("" ::: "memory");
      u16* sV = &lV[cur ^ 1][0] + t * 8;
#pragma unroll
      for (int c = 0; c < 4; c++) load_lds16(gV + j0n + c * 16 * 2048, sV + c * 2048);
      asm volatile("" ::: "memory");
    }

    if (j == qi) {
#pragma unroll
      for (int qt = 0; qt < 2; qt++) {
        const int q = qblk + qt * 16 + l15;
#pragma unroll
        for (int kvt = 0; kvt < 8; kvt++)
#pragma unroll
          for (int r = 0; r < 4; r++) {
            const int kv = j0 + kvt * 16 + quad * 4 + r;
            if (kv > q) accS[kvt][qt][r] = -3.0e38f;
          }
      }
    }

    // no-max softmax: p = exp2(s) raw; masked -> exp2(-3e38) = 0 (R2-verified)
    uint32_t pk01[2][8], pk23[2][8];
#pragma unroll
    for (int qt = 0; qt < 2; qt++) {
      float ts = 0.0f;
#pragma unroll
      for (int kvt = 0; kvt < 8; kvt++) {
        const float p0 = fexp2(accS[kvt][qt][0]);
        const float p1 = fexp2(accS[kvt][qt][1]);
        const float p2 = fexp2(accS[kvt][qt][2]);
        const float p3 = fexp2(accS[kvt][qt][3]);
        ts += (p0 + p1) + (p2 + p3);
        pk01[qt][kvt] = pkbf(p0, p1);
        pk23[qt][kvt] = pkbf(p2, p3);
      }
      lst[qt] += ts;   // lane-partial; cross-lane reduce deferred to epilogue
    }

    // V(j) ready: the 8 loads just issued for j+1 may remain in flight
    if (j < qi) asm volatile("s_waitcnt vmcnt(8)" ::: "memory");
    else        asm volatile("s_waitcnt vmcnt(0)" ::: "memory");
    __builtin_amdgcn_s_barrier();

    // ---- PV in two kv-half passes through per-wave lP ----
#pragma unroll
    for (int kvh = 0; kvh < 2; kvh++) {
#pragma unroll
      for (int qt = 0; qt < 2; qt++) {
        const int prow = (qt * 16 + l15) * 64;
#pragma unroll
        for (int kt = 0; kt < 4; kt++) {
          const int kvt = kvh * 4 + kt;
          const int slot = (kt * 2 + (quad >> 1)) ^ e7;
          u32x2 pk; pk.x = pk01[qt][kvt]; pk.y = pk23[qt][kvt];
          *(u32x2*)&myP[prow + slot * 8 + (quad & 1) * 4] = pk;
        }
      }
      asm volatile("s_waitcnt lgkmcnt(0)" ::: "memory");
      __builtin_amdgcn_s_setprio(1);
#pragma unroll
      for (int kk = 0; kk < 2; kk++) {
        const int kvc = kvh * 2 + kk;
        short8 pf[2];
#pragma unroll
        for (int qt = 0; qt < 2; qt++)
          pf[qt] = *(const short8*)&myP[(qt * 16 + l15) * 64 + (((kk * 4 + quad) ^ e7) << 3)];
#pragma unroll
        for (int dt = 0; dt < 4; dt++) {
          const short8 vf = *(const short8*)&cV[(dt * 16 + l15) * 128 + (((kvc * 4 + quad) ^ l15) << 3)];
#pragma unroll
          for (int qt = 0; qt < 2; qt++)
            accO[dt][qt] = __builtin_amdgcn_mfma_f32_16x16x32_bf16(vf, pf[qt], accO[dt][qt], 0, 0, 0);
        }
      }
      __builtin_amdgcn_s_setprio(0);
    }
  }

  // deferred cross-lane l reduction (butterfly over the 4 quads)
#pragma unroll
  for (int qt = 0; qt < 2; qt++) {
    lst[qt] += __shfl_xor(lst[qt], 16);
    lst[qt] += __shfl_xor(lst[qt], 32);
  }

#pragma unroll
  for (int qt = 0; qt < 2; qt++) {
    const float inv = 1.0f / lst[qt];
    const int q = qblk + qt * 16 + l15;
#pragma unroll
    for (int dt = 0; dt < 4; dt++) {
      u32x2 o;
      o.x = pkbf(accO[dt][qt][0] * inv, accO[dt][qt][1] * inv);
      o.y = pkbf(accO[dt][qt][2] * inv, accO[dt][qt][3] * inv);
      *(u32x2*)&Out[((size_t)b * 2048 + q) * 1024 + h * 64 + dt * 16 + quad * 4] = o;
    }
  }
}

// ---------------- launcher ----------------
extern "C" void kernel_launch(void* const* d_in, const int* in_sizes, int n_in,
                              void* d_out, int out_size, void* d_ws, size_t ws_size,
                              hipStream_t stream) {
  (void)in_sizes; (void)n_in; (void)out_size; (void)ws_size;
  const float* hidden = (const float*)d_in[0];
  const float* attn_w = (const float*)d_in[1];
  const float* attn_b = (const float*)d_in[2];
  const float* proj_w = (const float*)d_in[3];
  const float* proj_b = (const float*)d_in[4];
  ConvW cw;
  for (int i = 0; i < 9; i++) {
    cw.w[i] = (const float*)d_in[5 + 2 * i];
    cw.b[i] = (const float*)d_in[6 + 2 * i];
  }

  uint8_t* ws = (uint8_t*)d_ws;
  u16* h_bf   = (u16*)(ws + 0);          //  8,388,608 B
  u16* wqkvT  = (u16*)(ws + 8388608);    //  6,291,456 B
  u16* qkvpre = (u16*)(ws + 14680064);   // 25,165,824 B  [3][2][16][2048][64]
  u16* qpost  = (u16*)(ws + 39845888);   //  8,388,608 B  [2][16][2048][64]
  u16* kpost  = (u16*)(ws + 48234496);   //  8,388,608 B
  u16* vpostT = (u16*)(ws + 56623104);   //  8,388,608 B  [2][16][64][2048]
  u16* attno  = (u16*)(ws + 65011712);   //  8,388,608 B  [2][2048][1024]
  u16* wprojT = (u16*)(ws + 73400320);   //  2,097,152 B

  prep_fused<<<8192, 256, 0, stream>>>(hidden, h_bf, attn_w, wqkvT, proj_w, wprojT);
  gemm_bt<0, 128, 6><<<768, 256, 0, stream>>>(h_bf, wqkvT, attn_b, (void*)qkvpre, 4096, 3072, 1024);
  conv_mix<<<dim3(16, 16, 6), 256, 0, stream>>>(qkvpre, cw, qpost, kpost, vpostT);
  attn_fwd<<<dim3(512), 256, 0, stream>>>(qpost, kpost, vpostT, attno);
  gemm_bt<1, 64, 8><<<512, 256, 0, stream>>>(attno, wprojT, proj_b, d_out, 4096, 1024, 1024);
}